// Round 9
// baseline (106.228 us; speedup 1.0000x reference)
//
#include <hip/hip_runtime.h>

#define BB   128
#define TT   512
#define FF   40
#define WW   10
#define NS   503            // window starts (stride 1): T-W+1
#define NP   780            // F*(F-1)/2
#define SC   64             // steps per block (uniform; last chunk overlaps)
#define NCHUNK 8
#define ROWS (SC + WW - 1)  // 73 staged rows
#define NT   512            // threads per block (8 waves)
#define EPSC 1e-5f
#define C01  0.31622776601683794f   // sqrt(0.1)

// 512 threads x 2 pair-slots. Slot0: p = tid. Slot1: p = min(tid+512, 779) --
// lanes past the triangle all compute pair 779 and store identical values to
// the same address (coalesces to one transaction; deterministic). Phase 2 is
// fully branch-free: no exec-mask traffic, so slot1 LDS reads overlap slot0's
// lgkm wait. Output stores are nontemporal (pure streaming).
__global__ __launch_bounds__(NT, 8) void ts_corr_r9(const float* __restrict__ in,
                                                    float* __restrict__ out) {
    const int blk = blockIdx.x;
    const int b   = blk >> 3;              // / NCHUNK
    const int c   = blk & (NCHUNK - 1);
    const int s0  = (c == NCHUNK - 1) ? (NS - SC) : c * SC;   // 439 tail; overlap rows identical
    const int tid = threadIdx.x;

    __shared__ float  xs[SC + WW][FF];   // 74 rows (73 used + pad) = 11840 B
    __shared__ float2 st[SC][FF];        // (u*sqrt(0.1), m*u) = 20480 B

    // ---- phase 0: stage 73-row slab, float4 (730 quads) ----
    const float4* src4 = (const float4*)(in + ((size_t)b * TT + s0) * FF);
    float4* xs4 = (float4*)&xs[0][0];
    {
        xs4[tid] = src4[tid];                       // 0..511
        const int i2 = tid + NT;
        if (i2 < ROWS * FF / 4) xs4[i2] = src4[i2]; // 512..729
    }
    __syncthreads();

    // ---- phase 1: stats for all 64 steps (640 feature-quads) ----
    #pragma unroll
    for (int k = 0; k < 2; ++k) {
        const int qd = tid + k * NT;
        if (qd < SC * FF / 4) {
            const int t  = qd / 10;
            const int f0 = (qd - t * 10) * 4;
            float sx0=0,sx1=0,sx2=0,sx3=0, sq0=0,sq1=0,sq2=0,sq3=0;
            #pragma unroll
            for (int w = 0; w < WW; ++w) {
                const float4 x = *(const float4*)&xs[t + w][f0];
                sx0 += x.x; sx1 += x.y; sx2 += x.z; sx3 += x.w;
                sq0 += x.x*x.x; sq1 += x.y*x.y; sq2 += x.z*x.z; sq3 += x.w*x.w;
            }
            const float m0 = sx0*0.1f, m1 = sx1*0.1f, m2 = sx2*0.1f, m3 = sx3*0.1f;
            const float u0 = 1.f/(sqrtf(fmaxf(sq0*0.1f - m0*m0, 0.f)) + EPSC);
            const float u1 = 1.f/(sqrtf(fmaxf(sq1*0.1f - m1*m1, 0.f)) + EPSC);
            const float u2 = 1.f/(sqrtf(fmaxf(sq2*0.1f - m2*m2, 0.f)) + EPSC);
            const float u3 = 1.f/(sqrtf(fmaxf(sq3*0.1f - m3*m3, 0.f)) + EPSC);
            *(float4*)&st[t][f0]     = make_float4(u0*C01, m0*u0, u1*C01, m1*u1);
            *(float4*)&st[t][f0 + 2] = make_float4(u2*C01, m2*u2, u3*C01, m3*u3);
        }
    }

    // ---- pair setup + initial window (xs ready since phase-0 barrier) ----
    // slot0: p = tid; slot1: p = min(tid + 512, NP-1)  (dup-pair clamp)
    int pi[2], pj[2], poff[2];
    float sxy[2], ph[2][WW];
    #pragma unroll
    for (int k = 0; k < 2; ++k) {
        const int pp = min(tid + k * NT, NP - 1);
        poff[k] = pp;
        int i = (int)((79.0f - sqrtf((float)(6241 - 8 * pp))) * 0.5f);
        while (i > 0 && i * (79 - i) / 2 > pp) --i;
        while ((i + 1) * (79 - (i + 1)) / 2 <= pp) ++i;
        pi[k] = i;
        pj[k] = pp - i * (79 - i) / 2 + i + 1;
        float s = 0.f;
        #pragma unroll
        for (int w = 0; w < WW; ++w) {
            const float pr = xs[w][pi[k]] * xs[w][pj[k]];
            ph[k][w] = pr;
            s += pr;
        }
        sxy[k] = s;
    }
    __syncthreads();   // st ready; no barriers after this

    float* dstB = out + (size_t)(b * NS + s0) * NP;

// Two steps (TA, TA+1); U, DO2 are literals. Fully branch-free.
#define SLOT(K) do {                                                            \
    const int _ii = pi[K], _jj = pj[K];                                         \
    const float  _xiA = xs[_tA + WW][_ii], _xiB = xs[_tA + WW + 1][_ii];        \
    const float  _xjA = xs[_tA + WW][_jj], _xjB = xs[_tA + WW + 1][_jj];        \
    const float2 _siA = st[_tA][_ii],      _siB = st[_tA + 1][_ii];             \
    const float2 _sjA = st[_tA][_jj],      _sjB = st[_tA + 1][_jj];             \
    __builtin_nontemporal_store(sxy[K] * _siA.x * _sjA.x - _siA.y * _sjA.y,     \
                                _dA + poff[K]);                                 \
    const float _pn = _xiA * _xjA;                                              \
    sxy[K] += _pn - ph[K][U]; ph[K][U] = _pn;                                   \
    __builtin_nontemporal_store(sxy[K] * _siB.x * _sjB.x - _siB.y * _sjB.y,     \
                                _dB + poff[K]);                                 \
    if (DO2) {                                                                  \
        const float _p2 = _xiB * _xjB;                                          \
        sxy[K] += _p2 - ph[K][(U) + 1]; ph[K][(U) + 1] = _p2;                   \
    }                                                                           \
} while (0)

#define STEP2(UU, TA, DD) do {                                                  \
    const int _tA = (TA);                                                       \
    const int U = (UU);                                                         \
    const bool DO2 = (DD);                                                      \
    float* _dA = dstB + (size_t)_tA * NP;                                       \
    float* _dB = _dA + NP;                                                      \
    SLOT(0);                                                                    \
    SLOT(1);                                                                    \
} while (0)

    // ---- phase 2: t = 0..59 regular, epilogue t = 60..63 ----
    for (int t0 = 0; t0 < 60; t0 += WW) {
        STEP2(0, t0,     true);
        STEP2(2, t0 + 2, true);
        STEP2(4, t0 + 4, true);
        STEP2(6, t0 + 6, true);
        STEP2(8, t0 + 8, true);
    }
    STEP2(0, 60, true);
    STEP2(2, 62, false);
#undef STEP2
#undef SLOT
}

extern "C" void kernel_launch(void* const* d_in, const int* in_sizes, int n_in,
                              void* d_out, int out_size, void* d_ws, size_t ws_size,
                              hipStream_t stream) {
    const float* in = (const float*)d_in[0];
    float* out = (float*)d_out;
    ts_corr_r9<<<BB * NCHUNK, NT, 0, stream>>>(in, out);
}